// Round 3
// baseline (343.624 us; speedup 1.0000x reference)
//
#include <hip/hip_runtime.h>
#include <hip/hip_bf16.h>
#include <math.h>

// OLMoE sparse MoE block. fp32 storage, bf16 MFMA compute (32x32x16).
// T=1024, H=2048, I=1024, E=8, top-2, unweighted combine.
// Round 9: fat phases. BK=64, 1 barrier/phase, 16 MFMA/wave/phase.
// x pre-converted to bf16; A-tiles staged via global_load_lds (16B DMA)
// with XOR-swizzled source + swizzled read; B reg-staged fp32->bf16.
// R8 falsified the occupancy thesis (occ 10.7->20.8%, dur flat) =>
// per-interval latency floor; amortize it with 4x FLOP per interval.

#define NT 1024
#define HD 2048
#define ID 1024
#define NE 8
#define MAXTILES 24
#define BPITCH 72

typedef __bf16 v8bf __attribute__((ext_vector_type(8)));
typedef __bf16 v4bf __attribute__((ext_vector_type(4)));
typedef float v16f __attribute__((ext_vector_type(16)));

__device__ __forceinline__ v8bf cvt8(float4 a, float4 b) {
    v8bf v;
    v[0] = (__bf16)a.x; v[1] = (__bf16)a.y; v[2] = (__bf16)a.z; v[3] = (__bf16)a.w;
    v[4] = (__bf16)b.x; v[5] = (__bf16)b.y; v[6] = (__bf16)b.z; v[7] = (__bf16)b.w;
    return v;
}

__device__ __forceinline__ void gload16(const void* g, void* l) {
    __builtin_amdgcn_global_load_lds(
        (const __attribute__((address_space(1))) unsigned int*)g,
        (__attribute__((address_space(3))) unsigned int*)l, 16, 0, 0);
}

// ---------------- x -> bf16 ----------------
__global__ __launch_bounds__(256) void cvtx_kernel(
    const float* __restrict__ x, __bf16* __restrict__ xb)
{
    int t = blockIdx.x * 256 + threadIdx.x;   // 262144 threads, 8 elems each
    const float4* p = (const float4*)x + (size_t)t * 2;
    float4 a = p[0], b = p[1];
    *(v8bf*)(xb + (size_t)t * 8) = cvt8(a, b);
}

// ---------------- router: one wave per token ----------------
__global__ __launch_bounds__(256) void router_kernel(
    const float* __restrict__ x, const float* __restrict__ gw,
    float* __restrict__ logits_out, int* __restrict__ topids, int* __restrict__ counts)
{
    int wv = threadIdx.x >> 6, ln = threadIdx.x & 63;
    int t = blockIdx.x * 4 + wv;
    const float* xr = x + (size_t)t * HD + ln * 32;
    float4 xv[8];
#pragma unroll
    for (int i = 0; i < 8; i++) xv[i] = *(const float4*)(xr + i * 4);

    float lg[NE];
#pragma unroll
    for (int e = 0; e < NE; e++) {
        const float* wr = gw + (size_t)e * HD + ln * 32;
        float s = 0.f;
#pragma unroll
        for (int i = 0; i < 8; i++) {
            float4 w4 = *(const float4*)(wr + i * 4);
            s += xv[i].x * w4.x + xv[i].y * w4.y + xv[i].z * w4.z + xv[i].w * w4.w;
        }
#pragma unroll
        for (int off = 32; off > 0; off >>= 1) s += __shfl_down(s, off, 64);
        lg[e] = s;  // valid on lane 0
    }
    if (ln == 0) {
#pragma unroll
        for (int e = 0; e < NE; e++) logits_out[t * NE + e] = lg[e];
        int i1 = 0;
        for (int e = 1; e < NE; e++) if (lg[e] > lg[i1]) i1 = e;
        int i2 = -1;
        for (int e = 0; e < NE; e++) {
            if (e == i1) continue;
            if (i2 < 0 || lg[e] > lg[i2]) i2 = e;
        }
        topids[t * 2 + 0] = i1;
        topids[t * 2 + 1] = i2;
        atomicAdd(&counts[i1], 1);
        atomicAdd(&counts[i2], 1);
    }
}

// ---------------- scan + tile table ----------------
__global__ void scan_kernel(const int* __restrict__ counts, int* __restrict__ base,
                            int* __restrict__ cursor, int* __restrict__ tile_e,
                            int* __restrict__ tile_m)
{
    if (threadIdx.x == 0 && blockIdx.x == 0) {
        int s = 0, nt = 0;
        for (int e = 0; e < NE; e++) {
            base[e] = s; cursor[e] = s;
            for (int m0 = 0; m0 < counts[e]; m0 += 128) {
                tile_e[nt] = e; tile_m[nt] = m0; nt++;
            }
            s += counts[e];
        }
        for (int i = nt; i < MAXTILES; i++) tile_e[i] = -1;
    }
}

__global__ void assign_kernel(const int* __restrict__ topids, int* __restrict__ cursor,
                              int* __restrict__ rowtok, int* __restrict__ toppos)
{
    int t = blockIdx.x * blockDim.x + threadIdx.x;
    if (t < NT) {
#pragma unroll
        for (int s = 0; s < 2; s++) {
            int e = topids[t * 2 + s];
            int pos = atomicAdd(&cursor[e], 1);
            rowtok[pos] = t;
            toppos[t * 2 + s] = pos;
        }
    }
}

// ---------------- GEMM1: h = silu(X Wg) * (X Wu) ----------------
// tile M128 x N64, BK=64, 4 waves (each 64x32 out for g AND u).
// A: global_load_lds bf16, swizzled. B: reg-staged fp32->bf16, [n][k] LDS.
__global__ __launch_bounds__(256) void gemm1_kernel(
    const __bf16* __restrict__ xb, const float* __restrict__ wg, const float* __restrict__ wu,
    const int* __restrict__ counts, const int* __restrict__ basev, const int* __restrict__ rowtok,
    const int* __restrict__ tile_e, const int* __restrict__ tile_m,
    __bf16* __restrict__ hbuf)
{
    int ti = blockIdx.y;
    int e = tile_e[ti];
    if (e < 0) return;
    int m0 = tile_m[ti];
    int cnt = counts[e];
    int n0 = blockIdx.x * 64;
    int base = basev[e];

    __shared__ __align__(16) __bf16 Ald[2][128][64];
    __shared__ __align__(16) __bf16 Bg[2][64][BPITCH];
    __shared__ __align__(16) __bf16 Bu[2][64][BPITCH];

    int tid = threadIdx.x;
    int w = tid >> 6, ln = tid & 63, ml = ln & 31, hh = ln >> 5;
    int wm = (w & 1) * 64, wn = (w >> 1) * 32;

    // A staging: per wave 4 DMA instrs, each covers 8 rows (128B/row).
    // lane: row = w*32 + i*8 + (ln>>3); k-seg loaded = (ln&7) ^ (row&7).
    int lrow8 = ln >> 3, seg = ln & 7, gseg = seg ^ lrow8;
    const __bf16* aptr[4];
#pragma unroll
    for (int i = 0; i < 4; i++) {
        int idx = m0 + w * 32 + i * 8 + lrow8;
        int tok = (idx < cnt) ? rowtok[base + idx] : 0;
        aptr[i] = xb + (size_t)tok * HD + gseg * 8;
    }

    // B staging: thread covers n-quad bn=s_*4 (64 N), k-quad kp=P*4 (64 K), both mats
    int s_ = tid & 15, P = tid >> 4;
    int bn = s_ * 4, kp = P * 4;
    const float* wge = wg + (size_t)e * HD * ID + n0 + bn;
    const float* wue = wu + (size_t)e * HD * ID + n0 + bn;

    float4 rg[4], ru[4];

    auto b_load = [&](int step) {
        const float* pg = wge + (size_t)(step * 64 + kp) * ID;
        const float* pu = wue + (size_t)(step * 64 + kp) * ID;
#pragma unroll
        for (int i = 0; i < 4; i++) {
            rg[i] = *(const float4*)(pg + (size_t)i * ID);
            ru[i] = *(const float4*)(pu + (size_t)i * ID);
        }
    };
    auto b_store = [&](int B) {
        const float* gf = (const float*)rg;
        const float* uf = (const float*)ru;
#pragma unroll
        for (int j = 0; j < 4; j++) {
            v4bf pg, pu;
#pragma unroll
            for (int i = 0; i < 4; i++) {
                pg[i] = (__bf16)gf[i * 4 + j];
                pu[i] = (__bf16)uf[i * 4 + j];
            }
            *(v4bf*)&Bg[B][bn + j][kp] = pg;
            *(v4bf*)&Bu[B][bn + j][kp] = pu;
        }
    };
    auto a_issue = [&](int B, int step) {
#pragma unroll
        for (int i = 0; i < 4; i++)
            gload16(aptr[i] + step * 64, &Ald[B][w * 32 + i * 8][0]);
    };

    v16f accg0, accg1, accu0, accu1;
#pragma unroll
    for (int r = 0; r < 16; r++) { accg0[r] = 0.f; accg1[r] = 0.f; accu0[r] = 0.f; accu1[r] = 0.f; }

    auto do_mfma = [&](int B) {
        const __bf16* Af = &Ald[B][0][0];
        int x8 = (ml & 7) << 3;
        int ra = (wm + ml) << 6, rb = (wm + 32 + ml) << 6;
#pragma unroll
        for (int kh = 0; kh < 4; kh++) {
            int kb = kh * 16 + hh * 8;
            int ke = kb ^ x8;
            v8bf af0 = *(const v8bf*)&Af[ra + ke];
            v8bf af1 = *(const v8bf*)&Af[rb + ke];
            v8bf bg = *(const v8bf*)&Bg[B][wn + ml][kb];
            v8bf bu = *(const v8bf*)&Bu[B][wn + ml][kb];
            accg0 = __builtin_amdgcn_mfma_f32_32x32x16_bf16(af0, bg, accg0, 0, 0, 0);
            accg1 = __builtin_amdgcn_mfma_f32_32x32x16_bf16(af1, bg, accg1, 0, 0, 0);
            accu0 = __builtin_amdgcn_mfma_f32_32x32x16_bf16(af0, bu, accu0, 0, 0, 0);
            accu1 = __builtin_amdgcn_mfma_f32_32x32x16_bf16(af1, bu, accu1, 0, 0, 0);
        }
    };

    const int NS = HD / 64;  // 32 phases
    b_load(0);
    a_issue(0, 0);
    asm volatile("s_waitcnt vmcnt(0)" ::: "memory");
    b_store(0);
    b_load(1);
    __syncthreads();

    for (int s = 0; s < NS; s++) {
        int cur = s & 1, nxt = cur ^ 1;
        if (s + 1 < NS) {
            b_store(nxt);
            a_issue(nxt, s + 1);
            if (s + 2 < NS) b_load(s + 2);
        }
        do_mfma(cur);
        asm volatile("s_waitcnt vmcnt(0)" ::: "memory");
        __syncthreads();
    }

#pragma unroll
    for (int r = 0; r < 16; r++) {
        int dr = (r & 3) + 8 * (r >> 2) + 4 * hh;
        int row0 = wm + dr, row1 = wm + 32 + dr;
        int col = n0 + wn + ml;
        if (m0 + row0 < cnt) {
            float g = accg0[r], u = accu0[r];
            hbuf[(size_t)(base + m0 + row0) * ID + col] = (__bf16)(g / (1.f + __expf(-g)) * u);
        }
        if (m0 + row1 < cnt) {
            float g = accg1[r], u = accu1[r];
            hbuf[(size_t)(base + m0 + row1) * ID + col] = (__bf16)(g / (1.f + __expf(-g)) * u);
        }
    }
}

// ---------------- GEMM2: y = h Wd ----------------
// tile M128 x N128, BK=64, 4 waves (each 64x64 out).
__global__ __launch_bounds__(256) void gemm2_kernel(
    const __bf16* __restrict__ hbuf, const float* __restrict__ wd,
    const int* __restrict__ counts, const int* __restrict__ basev,
    const int* __restrict__ tile_e, const int* __restrict__ tile_m,
    __bf16* __restrict__ ybuf)
{
    int ti = blockIdx.y;
    int e = tile_e[ti];
    if (e < 0) return;
    int m0 = tile_m[ti];
    int cnt = counts[e];
    int n0 = blockIdx.x * 128;
    int base = basev[e];

    __shared__ __align__(16) __bf16 Ald[2][128][64];
    __shared__ __align__(16) __bf16 Bd[2][128][BPITCH];

    int tid = threadIdx.x;
    int w = tid >> 6, ln = tid & 63, ml = ln & 31, hh = ln >> 5;
    int wm = (w & 1) * 64, wn = (w >> 1) * 64;

    int lrow8 = ln >> 3, seg = ln & 7, gseg = seg ^ lrow8;
    const __bf16* aptr[4];
#pragma unroll
    for (int i = 0; i < 4; i++) {
        int idx = m0 + w * 32 + i * 8 + lrow8;
        int hr = base + (idx < cnt ? idx : cnt - 1);
        aptr[i] = hbuf + (size_t)hr * ID + gseg * 8;
    }

    // B staging: thread covers n-quad bn=s_*4 (128 N), k-oct kp=P*8 (64 K)
    int s_ = tid & 31, P = tid >> 5;
    int bn = s_ * 4, kp = P * 8;
    const float* wde = wd + (size_t)e * ID * HD + n0 + bn;

    float4 rd[8];

    auto b_load = [&](int step) {
        const float* p0 = wde + (size_t)(step * 64 + kp) * HD;
#pragma unroll
        for (int i = 0; i < 8; i++) rd[i] = *(const float4*)(p0 + (size_t)i * HD);
    };
    auto b_store = [&](int B) {
        const float* df = (const float*)rd;
#pragma unroll
        for (int j = 0; j < 4; j++) {
            v8bf pd;
#pragma unroll
            for (int i = 0; i < 8; i++) pd[i] = (__bf16)df[i * 4 + j];
            *(v8bf*)&Bd[B][bn + j][kp] = pd;
        }
    };
    auto a_issue = [&](int B, int step) {
#pragma unroll
        for (int i = 0; i < 4; i++)
            gload16(aptr[i] + step * 64, &Ald[B][w * 32 + i * 8][0]);
    };

    v16f acc00, acc10, acc01, acc11;
#pragma unroll
    for (int r = 0; r < 16; r++) { acc00[r] = 0.f; acc10[r] = 0.f; acc01[r] = 0.f; acc11[r] = 0.f; }

    auto do_mfma = [&](int B) {
        const __bf16* Af = &Ald[B][0][0];
        int x8 = (ml & 7) << 3;
        int ra = (wm + ml) << 6, rb = (wm + 32 + ml) << 6;
#pragma unroll
        for (int kh = 0; kh < 4; kh++) {
            int kb = kh * 16 + hh * 8;
            int ke = kb ^ x8;
            v8bf af0 = *(const v8bf*)&Af[ra + ke];
            v8bf af1 = *(const v8bf*)&Af[rb + ke];
            v8bf bf0 = *(const v8bf*)&Bd[B][wn + ml][kb];
            v8bf bf1 = *(const v8bf*)&Bd[B][wn + 32 + ml][kb];
            acc00 = __builtin_amdgcn_mfma_f32_32x32x16_bf16(af0, bf0, acc00, 0, 0, 0);
            acc10 = __builtin_amdgcn_mfma_f32_32x32x16_bf16(af1, bf0, acc10, 0, 0, 0);
            acc01 = __builtin_amdgcn_mfma_f32_32x32x16_bf16(af0, bf1, acc01, 0, 0, 0);
            acc11 = __builtin_amdgcn_mfma_f32_32x32x16_bf16(af1, bf1, acc11, 0, 0, 0);
        }
    };

    const int NS = ID / 64;  // 16 phases
    b_load(0);
    a_issue(0, 0);
    asm volatile("s_waitcnt vmcnt(0)" ::: "memory");
    b_store(0);
    b_load(1);
    __syncthreads();

    for (int s = 0; s < NS; s++) {
        int cur = s & 1, nxt = cur ^ 1;
        if (s + 1 < NS) {
            b_store(nxt);
            a_issue(nxt, s + 1);
            if (s + 2 < NS) b_load(s + 2);
        }
        do_mfma(cur);
        asm volatile("s_waitcnt vmcnt(0)" ::: "memory");
        __syncthreads();
    }

#pragma unroll
    for (int r = 0; r < 16; r++) {
        int dr = (r & 3) + 8 * (r >> 2) + 4 * hh;
        int row0 = wm + dr, row1 = wm + 32 + dr;
        if (m0 + row0 < cnt) {
            size_t o = (size_t)(base + m0 + row0) * HD + n0 + wn;
            ybuf[o + ml]      = (__bf16)acc00[r];
            ybuf[o + 32 + ml] = (__bf16)acc01[r];
        }
        if (m0 + row1 < cnt) {
            size_t o = (size_t)(base + m0 + row1) * HD + n0 + wn;
            ybuf[o + ml]      = (__bf16)acc10[r];
            ybuf[o + 32 + ml] = (__bf16)acc11[r];
        }
    }
}

// ---------------- combine ----------------
__global__ __launch_bounds__(256) void combine_kernel(
    const __bf16* __restrict__ ybuf, const int* __restrict__ toppos, float* __restrict__ out)
{
    int t = blockIdx.x;
    int tid = threadIdx.x;
    int p0 = toppos[t * 2 + 0];
    int p1 = toppos[t * 2 + 1];
    v8bf a = ((const v8bf*)(ybuf + (size_t)p0 * HD))[tid];
    v8bf b = ((const v8bf*)(ybuf + (size_t)p1 * HD))[tid];
    float4 o0, o1;
    o0.x = (float)a[0] + (float)b[0];
    o0.y = (float)a[1] + (float)b[1];
    o0.z = (float)a[2] + (float)b[2];
    o0.w = (float)a[3] + (float)b[3];
    o1.x = (float)a[4] + (float)b[4];
    o1.y = (float)a[5] + (float)b[5];
    o1.z = (float)a[6] + (float)b[6];
    o1.w = (float)a[7] + (float)b[7];
    float* orow = out + (size_t)t * HD + tid * 8;
    *(float4*)orow = o0;
    *(float4*)(orow + 4) = o1;
}

extern "C" void kernel_launch(void* const* d_in, const int* in_sizes, int n_in,
                              void* d_out, int out_size, void* d_ws, size_t ws_size,
                              hipStream_t stream)
{
    const float* x  = (const float*)d_in[0];
    const float* gw = (const float*)d_in[1];
    const float* wg = (const float*)d_in[2];
    const float* wu = (const float*)d_in[3];
    const float* wd = (const float*)d_in[4];
    float* out = (float*)d_out;
    float* logits = out + (size_t)NT * HD;

    char* ws = (char*)d_ws;
    int* counts = (int*)(ws + 0);
    int* base   = (int*)(ws + 64);
    int* cursor = (int*)(ws + 128);
    int* tile_e = (int*)(ws + 256);   // MAXTILES ints
    int* tile_m = (int*)(ws + 384);   // MAXTILES ints
    int* topids = (int*)(ws + 1024);
    int* toppos = (int*)(ws + 1024 + 8192);
    int* rowtok = (int*)(ws + 1024 + 16384);
    __bf16* hbuf = (__bf16*)(ws + 32768);                            // [2048,1024] bf16 = 4 MB
    __bf16* ybuf = (__bf16*)(ws + 32768 + (size_t)2048 * ID * 2);    // [2048,2048] bf16 = 8 MB
    __bf16* xb   = (__bf16*)(ws + 32768 + (size_t)2048 * ID * 2 + (size_t)2048 * HD * 2);  // [1024,2048] bf16 = 4 MB

    hipMemsetAsync(ws, 0, 256, stream);
    cvtx_kernel<<<NT * HD / (256 * 8), 256, 0, stream>>>(x, xb);
    router_kernel<<<NT / 4, 256, 0, stream>>>(x, gw, logits, topids, counts);
    scan_kernel<<<1, 64, 0, stream>>>(counts, base, cursor, tile_e, tile_m);
    assign_kernel<<<4, 256, 0, stream>>>(topids, cursor, rowtok, toppos);
    gemm1_kernel<<<dim3(ID / 64, MAXTILES), 256, 0, stream>>>(xb, wg, wu, counts, base, rowtok, tile_e, tile_m, hbuf);
    gemm2_kernel<<<dim3(HD / 128, MAXTILES), 256, 0, stream>>>(hbuf, wd, counts, base, tile_e, tile_m, ybuf);
    combine_kernel<<<NT, 256, 0, stream>>>(ybuf, toppos, out);
}

// Round 4
// 329.941 us; speedup vs baseline: 1.0415x; 1.0415x over previous
//
#include <hip/hip_runtime.h>
#include <hip/hip_bf16.h>
#include <math.h>

// OLMoE sparse MoE block. fp32 storage, bf16 MFMA compute (32x32x16).
// T=1024, H=2048, I=1024, E=8, top-2, unweighted combine.
// Round 10: counted-vmcnt pipeline. R9's __syncthreads() lowers to
// s_waitcnt vmcnt(0) lgkmcnt(0) + s_barrier => every phase drained the
// just-issued B-loads/DMAs (full latency exposed; only 1 wave/SIMD to
// hide it). Replace with s_waitcnt vmcnt(8) lgkmcnt(0) + raw s_barrier:
// the 8 B register-loads stay in flight across the barrier (T4).
// Geometry identical to R9 (BK=64 fat phases, A via global_load_lds).

#define NT 1024
#define HD 2048
#define ID 1024
#define NE 8
#define MAXTILES 24
#define BPITCH 72

typedef __bf16 v8bf __attribute__((ext_vector_type(8)));
typedef __bf16 v4bf __attribute__((ext_vector_type(4)));
typedef float v16f __attribute__((ext_vector_type(16)));

__device__ __forceinline__ v8bf cvt8(float4 a, float4 b) {
    v8bf v;
    v[0] = (__bf16)a.x; v[1] = (__bf16)a.y; v[2] = (__bf16)a.z; v[3] = (__bf16)a.w;
    v[4] = (__bf16)b.x; v[5] = (__bf16)b.y; v[6] = (__bf16)b.z; v[7] = (__bf16)b.w;
    return v;
}

__device__ __forceinline__ void gload16(const void* g, void* l) {
    __builtin_amdgcn_global_load_lds(
        (const __attribute__((address_space(1))) unsigned int*)g,
        (__attribute__((address_space(3))) unsigned int*)l, 16, 0, 0);
}

// ---------------- x -> bf16 ----------------
__global__ __launch_bounds__(256) void cvtx_kernel(
    const float* __restrict__ x, __bf16* __restrict__ xb)
{
    int t = blockIdx.x * 256 + threadIdx.x;   // 262144 threads, 8 elems each
    const float4* p = (const float4*)x + (size_t)t * 2;
    float4 a = p[0], b = p[1];
    *(v8bf*)(xb + (size_t)t * 8) = cvt8(a, b);
}

// ---------------- router: one wave per token ----------------
__global__ __launch_bounds__(256) void router_kernel(
    const float* __restrict__ x, const float* __restrict__ gw,
    float* __restrict__ logits_out, int* __restrict__ topids, int* __restrict__ counts)
{
    int wv = threadIdx.x >> 6, ln = threadIdx.x & 63;
    int t = blockIdx.x * 4 + wv;
    const float* xr = x + (size_t)t * HD + ln * 32;
    float4 xv[8];
#pragma unroll
    for (int i = 0; i < 8; i++) xv[i] = *(const float4*)(xr + i * 4);

    float lg[NE];
#pragma unroll
    for (int e = 0; e < NE; e++) {
        const float* wr = gw + (size_t)e * HD + ln * 32;
        float s = 0.f;
#pragma unroll
        for (int i = 0; i < 8; i++) {
            float4 w4 = *(const float4*)(wr + i * 4);
            s += xv[i].x * w4.x + xv[i].y * w4.y + xv[i].z * w4.z + xv[i].w * w4.w;
        }
#pragma unroll
        for (int off = 32; off > 0; off >>= 1) s += __shfl_down(s, off, 64);
        lg[e] = s;  // valid on lane 0
    }
    if (ln == 0) {
#pragma unroll
        for (int e = 0; e < NE; e++) logits_out[t * NE + e] = lg[e];
        int i1 = 0;
        for (int e = 1; e < NE; e++) if (lg[e] > lg[i1]) i1 = e;
        int i2 = -1;
        for (int e = 0; e < NE; e++) {
            if (e == i1) continue;
            if (i2 < 0 || lg[e] > lg[i2]) i2 = e;
        }
        topids[t * 2 + 0] = i1;
        topids[t * 2 + 1] = i2;
        atomicAdd(&counts[i1], 1);
        atomicAdd(&counts[i2], 1);
    }
}

// ---------------- scan + tile table ----------------
__global__ void scan_kernel(const int* __restrict__ counts, int* __restrict__ base,
                            int* __restrict__ cursor, int* __restrict__ tile_e,
                            int* __restrict__ tile_m)
{
    if (threadIdx.x == 0 && blockIdx.x == 0) {
        int s = 0, nt = 0;
        for (int e = 0; e < NE; e++) {
            base[e] = s; cursor[e] = s;
            for (int m0 = 0; m0 < counts[e]; m0 += 128) {
                tile_e[nt] = e; tile_m[nt] = m0; nt++;
            }
            s += counts[e];
        }
        for (int i = nt; i < MAXTILES; i++) tile_e[i] = -1;
    }
}

__global__ void assign_kernel(const int* __restrict__ topids, int* __restrict__ cursor,
                              int* __restrict__ rowtok, int* __restrict__ toppos)
{
    int t = blockIdx.x * blockDim.x + threadIdx.x;
    if (t < NT) {
#pragma unroll
        for (int s = 0; s < 2; s++) {
            int e = topids[t * 2 + s];
            int pos = atomicAdd(&cursor[e], 1);
            rowtok[pos] = t;
            toppos[t * 2 + s] = pos;
        }
    }
}

// ---------------- GEMM1: h = silu(X Wg) * (X Wu) ----------------
// tile M128 x N64, BK=64, 4 waves (each 64x32 out for g AND u).
__global__ __launch_bounds__(256) void gemm1_kernel(
    const __bf16* __restrict__ xb, const float* __restrict__ wg, const float* __restrict__ wu,
    const int* __restrict__ counts, const int* __restrict__ basev, const int* __restrict__ rowtok,
    const int* __restrict__ tile_e, const int* __restrict__ tile_m,
    __bf16* __restrict__ hbuf)
{
    int ti = blockIdx.y;
    int e = tile_e[ti];
    if (e < 0) return;
    int m0 = tile_m[ti];
    int cnt = counts[e];
    int n0 = blockIdx.x * 64;
    int base = basev[e];

    __shared__ __align__(16) __bf16 Ald[2][128][64];
    __shared__ __align__(16) __bf16 Bg[2][64][BPITCH];
    __shared__ __align__(16) __bf16 Bu[2][64][BPITCH];

    int tid = threadIdx.x;
    int w = tid >> 6, ln = tid & 63, ml = ln & 31, hh = ln >> 5;
    int wm = (w & 1) * 64, wn = (w >> 1) * 32;

    // A staging: per wave 4 DMA instrs, each covers 8 rows (128B/row).
    int lrow8 = ln >> 3, seg = ln & 7, gseg = seg ^ lrow8;
    const __bf16* aptr[4];
#pragma unroll
    for (int i = 0; i < 4; i++) {
        int idx = m0 + w * 32 + i * 8 + lrow8;
        int tok = (idx < cnt) ? rowtok[base + idx] : 0;
        aptr[i] = xb + (size_t)tok * HD + gseg * 8;
    }

    // B staging: thread covers n-quad bn=s_*4 (64 N), k-quad kp=P*4 (64 K), both mats
    int s_ = tid & 15, P = tid >> 4;
    int bn = s_ * 4, kp = P * 4;
    const float* wge = wg + (size_t)e * HD * ID + n0 + bn;
    const float* wue = wu + (size_t)e * HD * ID + n0 + bn;

    float4 rg[4], ru[4];

    auto b_load = [&](int step) {
        const float* pg = wge + (size_t)(step * 64 + kp) * ID;
        const float* pu = wue + (size_t)(step * 64 + kp) * ID;
#pragma unroll
        for (int i = 0; i < 4; i++) {
            rg[i] = *(const float4*)(pg + (size_t)i * ID);
            ru[i] = *(const float4*)(pu + (size_t)i * ID);
        }
    };
    auto b_store = [&](int B) {
        const float* gf = (const float*)rg;
        const float* uf = (const float*)ru;
#pragma unroll
        for (int j = 0; j < 4; j++) {
            v4bf pg, pu;
#pragma unroll
            for (int i = 0; i < 4; i++) {
                pg[i] = (__bf16)gf[i * 4 + j];
                pu[i] = (__bf16)uf[i * 4 + j];
            }
            *(v4bf*)&Bg[B][bn + j][kp] = pg;
            *(v4bf*)&Bu[B][bn + j][kp] = pu;
        }
    };
    auto a_issue = [&](int B, int step) {
#pragma unroll
        for (int i = 0; i < 4; i++)
            gload16(aptr[i] + step * 64, &Ald[B][w * 32 + i * 8][0]);
    };

    v16f accg0, accg1, accu0, accu1;
#pragma unroll
    for (int r = 0; r < 16; r++) { accg0[r] = 0.f; accg1[r] = 0.f; accu0[r] = 0.f; accu1[r] = 0.f; }

    auto do_mfma = [&](int B) {
        const __bf16* Af = &Ald[B][0][0];
        int x8 = (ml & 7) << 3;
        int ra = (wm + ml) << 6, rb = (wm + 32 + ml) << 6;
#pragma unroll
        for (int kh = 0; kh < 4; kh++) {
            int kb = kh * 16 + hh * 8;
            int ke = kb ^ x8;
            v8bf af0 = *(const v8bf*)&Af[ra + ke];
            v8bf af1 = *(const v8bf*)&Af[rb + ke];
            v8bf bg = *(const v8bf*)&Bg[B][wn + ml][kb];
            v8bf bu = *(const v8bf*)&Bu[B][wn + ml][kb];
            accg0 = __builtin_amdgcn_mfma_f32_32x32x16_bf16(af0, bg, accg0, 0, 0, 0);
            accg1 = __builtin_amdgcn_mfma_f32_32x32x16_bf16(af1, bg, accg1, 0, 0, 0);
            accu0 = __builtin_amdgcn_mfma_f32_32x32x16_bf16(af0, bu, accu0, 0, 0, 0);
            accu1 = __builtin_amdgcn_mfma_f32_32x32x16_bf16(af1, bu, accu1, 0, 0, 0);
        }
    };

    const int NS = HD / 64;  // 32 phases
    b_load(0);
    a_issue(0, 0);
    asm volatile("s_waitcnt vmcnt(0)" ::: "memory");
    b_store(0);
    b_load(1);
    asm volatile("s_waitcnt lgkmcnt(0)" ::: "memory");
    __builtin_amdgcn_s_barrier();

    for (int s = 0; s < NS; s++) {
        int cur = s & 1, nxt = cur ^ 1;
        if (s + 1 < NS) {
            b_store(nxt);
            a_issue(nxt, s + 1);
            __builtin_amdgcn_sched_barrier(0);   // pin: DMAs before b_load in vm queue
            if (s + 2 < NS) b_load(s + 2);
        }
        do_mfma(cur);
        if (s + 2 < NS) {
            // vm queue: [4 DMA][8 b_load] -> wait DMAs only, loads fly across barrier
            asm volatile("s_waitcnt vmcnt(8) lgkmcnt(0)" ::: "memory");
        } else {
            asm volatile("s_waitcnt vmcnt(0) lgkmcnt(0)" ::: "memory");
        }
        __builtin_amdgcn_s_barrier();
    }

#pragma unroll
    for (int r = 0; r < 16; r++) {
        int dr = (r & 3) + 8 * (r >> 2) + 4 * hh;
        int row0 = wm + dr, row1 = wm + 32 + dr;
        int col = n0 + wn + ml;
        if (m0 + row0 < cnt) {
            float g = accg0[r], u = accu0[r];
            hbuf[(size_t)(base + m0 + row0) * ID + col] = (__bf16)(g / (1.f + __expf(-g)) * u);
        }
        if (m0 + row1 < cnt) {
            float g = accg1[r], u = accu1[r];
            hbuf[(size_t)(base + m0 + row1) * ID + col] = (__bf16)(g / (1.f + __expf(-g)) * u);
        }
    }
}

// ---------------- GEMM2: y = h Wd ----------------
// tile M128 x N128, BK=64, 4 waves (each 64x64 out).
__global__ __launch_bounds__(256) void gemm2_kernel(
    const __bf16* __restrict__ hbuf, const float* __restrict__ wd,
    const int* __restrict__ counts, const int* __restrict__ basev,
    const int* __restrict__ tile_e, const int* __restrict__ tile_m,
    __bf16* __restrict__ ybuf)
{
    int ti = blockIdx.y;
    int e = tile_e[ti];
    if (e < 0) return;
    int m0 = tile_m[ti];
    int cnt = counts[e];
    int n0 = blockIdx.x * 128;
    int base = basev[e];

    __shared__ __align__(16) __bf16 Ald[2][128][64];
    __shared__ __align__(16) __bf16 Bd[2][128][BPITCH];

    int tid = threadIdx.x;
    int w = tid >> 6, ln = tid & 63, ml = ln & 31, hh = ln >> 5;
    int wm = (w & 1) * 64, wn = (w >> 1) * 64;

    int lrow8 = ln >> 3, seg = ln & 7, gseg = seg ^ lrow8;
    const __bf16* aptr[4];
#pragma unroll
    for (int i = 0; i < 4; i++) {
        int idx = m0 + w * 32 + i * 8 + lrow8;
        int hr = base + (idx < cnt ? idx : cnt - 1);
        aptr[i] = hbuf + (size_t)hr * ID + gseg * 8;
    }

    // B staging: thread covers n-quad bn=s_*4 (128 N), k-oct kp=P*8 (64 K)
    int s_ = tid & 31, P = tid >> 5;
    int bn = s_ * 4, kp = P * 8;
    const float* wde = wd + (size_t)e * ID * HD + n0 + bn;

    float4 rd[8];

    auto b_load = [&](int step) {
        const float* p0 = wde + (size_t)(step * 64 + kp) * HD;
#pragma unroll
        for (int i = 0; i < 8; i++) rd[i] = *(const float4*)(p0 + (size_t)i * HD);
    };
    auto b_store = [&](int B) {
        const float* df = (const float*)rd;
#pragma unroll
        for (int j = 0; j < 4; j++) {
            v8bf pd;
#pragma unroll
            for (int i = 0; i < 8; i++) pd[i] = (__bf16)df[i * 4 + j];
            *(v8bf*)&Bd[B][bn + j][kp] = pd;
        }
    };
    auto a_issue = [&](int B, int step) {
#pragma unroll
        for (int i = 0; i < 4; i++)
            gload16(aptr[i] + step * 64, &Ald[B][w * 32 + i * 8][0]);
    };

    v16f acc00, acc10, acc01, acc11;
#pragma unroll
    for (int r = 0; r < 16; r++) { acc00[r] = 0.f; acc10[r] = 0.f; acc01[r] = 0.f; acc11[r] = 0.f; }

    auto do_mfma = [&](int B) {
        const __bf16* Af = &Ald[B][0][0];
        int x8 = (ml & 7) << 3;
        int ra = (wm + ml) << 6, rb = (wm + 32 + ml) << 6;
#pragma unroll
        for (int kh = 0; kh < 4; kh++) {
            int kb = kh * 16 + hh * 8;
            int ke = kb ^ x8;
            v8bf af0 = *(const v8bf*)&Af[ra + ke];
            v8bf af1 = *(const v8bf*)&Af[rb + ke];
            v8bf bf0 = *(const v8bf*)&Bd[B][wn + ml][kb];
            v8bf bf1 = *(const v8bf*)&Bd[B][wn + 32 + ml][kb];
            acc00 = __builtin_amdgcn_mfma_f32_32x32x16_bf16(af0, bf0, acc00, 0, 0, 0);
            acc10 = __builtin_amdgcn_mfma_f32_32x32x16_bf16(af1, bf0, acc10, 0, 0, 0);
            acc01 = __builtin_amdgcn_mfma_f32_32x32x16_bf16(af0, bf1, acc01, 0, 0, 0);
            acc11 = __builtin_amdgcn_mfma_f32_32x32x16_bf16(af1, bf1, acc11, 0, 0, 0);
        }
    };

    const int NS = ID / 64;  // 16 phases
    b_load(0);
    a_issue(0, 0);
    asm volatile("s_waitcnt vmcnt(0)" ::: "memory");
    b_store(0);
    b_load(1);
    asm volatile("s_waitcnt lgkmcnt(0)" ::: "memory");
    __builtin_amdgcn_s_barrier();

    for (int s = 0; s < NS; s++) {
        int cur = s & 1, nxt = cur ^ 1;
        if (s + 1 < NS) {
            b_store(nxt);
            a_issue(nxt, s + 1);
            __builtin_amdgcn_sched_barrier(0);
            if (s + 2 < NS) b_load(s + 2);
        }
        do_mfma(cur);
        if (s + 2 < NS) {
            asm volatile("s_waitcnt vmcnt(8) lgkmcnt(0)" ::: "memory");
        } else {
            asm volatile("s_waitcnt vmcnt(0) lgkmcnt(0)" ::: "memory");
        }
        __builtin_amdgcn_s_barrier();
    }

#pragma unroll
    for (int r = 0; r < 16; r++) {
        int dr = (r & 3) + 8 * (r >> 2) + 4 * hh;
        int row0 = wm + dr, row1 = wm + 32 + dr;
        if (m0 + row0 < cnt) {
            size_t o = (size_t)(base + m0 + row0) * HD + n0 + wn;
            ybuf[o + ml]      = (__bf16)acc00[r];
            ybuf[o + 32 + ml] = (__bf16)acc01[r];
        }
        if (m0 + row1 < cnt) {
            size_t o = (size_t)(base + m0 + row1) * HD + n0 + wn;
            ybuf[o + ml]      = (__bf16)acc10[r];
            ybuf[o + 32 + ml] = (__bf16)acc11[r];
        }
    }
}

// ---------------- combine ----------------
__global__ __launch_bounds__(256) void combine_kernel(
    const __bf16* __restrict__ ybuf, const int* __restrict__ toppos, float* __restrict__ out)
{
    int t = blockIdx.x;
    int tid = threadIdx.x;
    int p0 = toppos[t * 2 + 0];
    int p1 = toppos[t * 2 + 1];
    v8bf a = ((const v8bf*)(ybuf + (size_t)p0 * HD))[tid];
    v8bf b = ((const v8bf*)(ybuf + (size_t)p1 * HD))[tid];
    float4 o0, o1;
    o0.x = (float)a[0] + (float)b[0];
    o0.y = (float)a[1] + (float)b[1];
    o0.z = (float)a[2] + (float)b[2];
    o0.w = (float)a[3] + (float)b[3];
    o1.x = (float)a[4] + (float)b[4];
    o1.y = (float)a[5] + (float)b[5];
    o1.z = (float)a[6] + (float)b[6];
    o1.w = (float)a[7] + (float)b[7];
    float* orow = out + (size_t)t * HD + tid * 8;
    *(float4*)orow = o0;
    *(float4*)(orow + 4) = o1;
}

extern "C" void kernel_launch(void* const* d_in, const int* in_sizes, int n_in,
                              void* d_out, int out_size, void* d_ws, size_t ws_size,
                              hipStream_t stream)
{
    const float* x  = (const float*)d_in[0];
    const float* gw = (const float*)d_in[1];
    const float* wg = (const float*)d_in[2];
    const float* wu = (const float*)d_in[3];
    const float* wd = (const float*)d_in[4];
    float* out = (float*)d_out;
    float* logits = out + (size_t)NT * HD;

    char* ws = (char*)d_ws;
    int* counts = (int*)(ws + 0);
    int* base   = (int*)(ws + 64);
    int* cursor = (int*)(ws + 128);
    int* tile_e = (int*)(ws + 256);   // MAXTILES ints
    int* tile_m = (int*)(ws + 384);   // MAXTILES ints
    int* topids = (int*)(ws + 1024);
    int* toppos = (int*)(ws + 1024 + 8192);
    int* rowtok = (int*)(ws + 1024 + 16384);
    __bf16* hbuf = (__bf16*)(ws + 32768);                            // [2048,1024] bf16 = 4 MB
    __bf16* ybuf = (__bf16*)(ws + 32768 + (size_t)2048 * ID * 2);    // [2048,2048] bf16 = 8 MB
    __bf16* xb   = (__bf16*)(ws + 32768 + (size_t)2048 * ID * 2 + (size_t)2048 * HD * 2);  // [1024,2048] bf16 = 4 MB

    hipMemsetAsync(ws, 0, 256, stream);
    cvtx_kernel<<<NT * HD / (256 * 8), 256, 0, stream>>>(x, xb);
    router_kernel<<<NT / 4, 256, 0, stream>>>(x, gw, logits, topids, counts);
    scan_kernel<<<1, 64, 0, stream>>>(counts, base, cursor, tile_e, tile_m);
    assign_kernel<<<4, 256, 0, stream>>>(topids, cursor, rowtok, toppos);
    gemm1_kernel<<<dim3(ID / 64, MAXTILES), 256, 0, stream>>>(xb, wg, wu, counts, base, rowtok, tile_e, tile_m, hbuf);
    gemm2_kernel<<<dim3(HD / 128, MAXTILES), 256, 0, stream>>>(hbuf, wd, counts, base, tile_e, tile_m, ybuf);
    combine_kernel<<<NT, 256, 0, stream>>>(ybuf, toppos, out);
}